// Round 2
// 189.660 us; speedup vs baseline: 1.0150x; 1.0150x over previous
//
#include <hip/hip_runtime.h>

// Problem dims (fixed by setup_inputs)
#define BATCH 4
#define HH 128
#define WW 128
#define CC 128
#define BIN 64
#define NPIX (BATCH * HH * WW)   // 65536

typedef short bf16x8 __attribute__((ext_vector_type(8)));
typedef float f32x4 __attribute__((ext_vector_type(4)));

// round-to-nearest-even bf16 bits of f
__device__ __forceinline__ unsigned bf_hi(float f) {
    unsigned u = __float_as_uint(f);
    return (u + 0x7fffu + ((u >> 16) & 1u)) >> 16;
}
// A-operand split: per c, k' slots [4c..4c+3] = [xh, xh, xl, xl]
__device__ __forceinline__ uint2 split_aa(float f) {
    unsigned hb = bf_hi(f);
    float lo = f - __uint_as_float(hb << 16);
    unsigned lb = bf_hi(lo);
    return make_uint2(hb | (hb << 16), lb | (lb << 16));
}
// B-operand split: per c, k' slots = [wh, wl, wh, wl] -> same uint twice
__device__ __forceinline__ unsigned split_b(float f) {
    unsigned hb = bf_hi(f);
    float lo = f - __uint_as_float(hb << 16);
    unsigned lb = bf_hi(lo);
    return hb | (lb << 16);
}

// ---------------------------------------------------------------------------
// Kernel 1: 1x1 conv == GEMM via split-bf16 MFMA.
// Y[p][d] = sum_c X[p][c]*W[c][d], fp32 reproduced as (xh+xl)*(wh+wl),
// K'=512 (4 bf16 slots per c). 128px x 128d tile, K' chunked by 64 (16 c).
// v2: register-prefetch pipeline — global loads for chunk k+1 are issued
// right after the stage->MFMA barrier, so HBM/L2 latency hides under the
// MFMA + ds_read phase (the next top-of-loop barrier drains them).
// __launch_bounds__(256,4): 4 blocks/CU (LDS 36.9KB x4 = 147KB), grid 1024
// = exactly 4 blocks/CU.
// ---------------------------------------------------------------------------
#define AROW 72   // shorts per LDS row (64 k' + 8 pad)

__global__ __launch_bounds__(256, 4)
void conv_mfma_kernel(const float* __restrict__ Xm, const float* __restrict__ Xr,
                      const float* __restrict__ Wm, const float* __restrict__ Wr,
                      float* __restrict__ Ym, float* __restrict__ Yr) {
    const float* __restrict__ X = blockIdx.y ? Xr : Xm;
    const float* __restrict__ W = blockIdx.y ? Wr : Wm;
    float* __restrict__ Y       = blockIdx.y ? Yr : Ym;

    __shared__ unsigned short AT[128 * AROW];   // [px][k'] 18 KB
    __shared__ unsigned short BT[128 * AROW];   // [d][k']  18 KB

    const int t  = threadIdx.x;
    const int wv = t >> 6;
    const int l  = t & 63;
    const int wm = (wv >> 1) * 64;   // wave's px-quadrant
    const int wn = (wv & 1) * 64;    // wave's d-quadrant
    const int lr = l & 15;
    const int lq = l >> 4;
    const int p_base = blockIdx.x * 128;

    const int px = t >> 1, ahalf = t & 1;   // A staging: 2 thr/px, 8 c each
    const int d  = t & 127, bq = t >> 7;    // B staging: 2 thr/d, 8 c each

    f32x4 acc[4][4] = {};

    const float* xbase = X + (size_t)(p_base + px) * CC + ahalf * 8;

    // ---- prologue: prefetch chunk 0 into registers ----
    float4 xa0 = *(const float4*)(xbase);
    float4 xa1 = *(const float4*)(xbase + 4);
    float wb[8];
#pragma unroll
    for (int j = 0; j < 2; ++j) {
        const int cg = bq * 2 + j;
        const float* wp = W + (size_t)(cg * 4) * CC + d;
        wb[j * 4 + 0] = wp[0];
        wb[j * 4 + 1] = wp[CC];
        wb[j * 4 + 2] = wp[2 * CC];
        wb[j * 4 + 3] = wp[3 * CC];
    }

    for (int kc = 0; kc < CC; kc += 16) {   // 16 c per chunk = 64 k'
        __syncthreads();                    // prev MFMA reads done
        // ---- stage A from regs (fp32 -> [h,h,l,l] bf16) ----
        {
            unsigned short* arow = &AT[px * AROW + ahalf * 32];
            {
                uint2 a0 = split_aa(xa0.x), a1 = split_aa(xa0.y),
                      a2 = split_aa(xa0.z), a3 = split_aa(xa0.w);
                *(uint4*)(arow)     = make_uint4(a0.x, a0.y, a1.x, a1.y);
                *(uint4*)(arow + 8) = make_uint4(a2.x, a2.y, a3.x, a3.y);
            }
            {
                uint2 a0 = split_aa(xa1.x), a1 = split_aa(xa1.y),
                      a2 = split_aa(xa1.z), a3 = split_aa(xa1.w);
                *(uint4*)(arow + 16) = make_uint4(a0.x, a0.y, a1.x, a1.y);
                *(uint4*)(arow + 24) = make_uint4(a2.x, a2.y, a3.x, a3.y);
            }
        }
        // ---- stage B from regs (fp32 -> [h,l,h,l] bf16, [d][k']) ----
        {
#pragma unroll
            for (int j = 0; j < 2; ++j) {
                const int cg = bq * 2 + j;
                unsigned b0 = split_b(wb[j * 4 + 0]);
                unsigned b1 = split_b(wb[j * 4 + 1]);
                unsigned b2 = split_b(wb[j * 4 + 2]);
                unsigned b3 = split_b(wb[j * 4 + 3]);
                unsigned short* brow = &BT[d * AROW + cg * 16];
                *(uint4*)(brow)     = make_uint4(b0, b0, b1, b1);
                *(uint4*)(brow + 8) = make_uint4(b2, b2, b3, b3);
            }
        }
        __syncthreads();
        // ---- prefetch chunk kc+16 (overlaps MFMA below) ----
        if (kc + 16 < CC) {
            const float* xp = xbase + kc + 16;
            xa0 = *(const float4*)(xp);
            xa1 = *(const float4*)(xp + 4);
#pragma unroll
            for (int j = 0; j < 2; ++j) {
                const int cg = bq * 2 + j;
                const float* wp = W + (size_t)(kc + 16 + cg * 4) * CC + d;
                wb[j * 4 + 0] = wp[0];
                wb[j * 4 + 1] = wp[CC];
                wb[j * 4 + 2] = wp[2 * CC];
                wb[j * 4 + 3] = wp[3 * CC];
            }
        }
        // ---- MFMA: 2 k-steps of 32 ----
#pragma unroll
        for (int ks = 0; ks < 2; ++ks) {
            bf16x8 af[4], bfr[4];
#pragma unroll
            for (int mi = 0; mi < 4; ++mi)
                af[mi] = *(const bf16x8*)&AT[(wm + mi * 16 + lr) * AROW + ks * 32 + lq * 8];
#pragma unroll
            for (int ni = 0; ni < 4; ++ni)
                bfr[ni] = *(const bf16x8*)&BT[(wn + ni * 16 + lr) * AROW + ks * 32 + lq * 8];
#pragma unroll
            for (int mi = 0; mi < 4; ++mi)
#pragma unroll
                for (int ni = 0; ni < 4; ++ni)
                    acc[mi][ni] = __builtin_amdgcn_mfma_f32_16x16x32_bf16(
                        af[mi], bfr[ni], acc[mi][ni], 0, 0, 0);
        }
    }

    // epilogue: C/D layout col=lane&15, row=(lane>>4)*4+reg
#pragma unroll
    for (int mi = 0; mi < 4; ++mi)
#pragma unroll
        for (int ni = 0; ni < 4; ++ni)
#pragma unroll
            for (int reg = 0; reg < 4; ++reg) {
                const int row = p_base + wm + mi * 16 + lq * 4 + reg;
                Y[(size_t)row * CC + wn + ni * 16 + lr] = acc[mi][ni][reg];
            }
}

// ---------------------------------------------------------------------------
// Kernel 2: local 5x5 attention, LDS-tiled with async prefetch.
// v2: 4 threads per pixel (512 thr/block) to break the occupancy cap — with
// 1 thr/px the whole problem is only 1024 waves = 4 waves/CU (9% occupancy,
// latency-bound). Lanes 4i..4i+3 split the 32-ch chunk (8 ch each) for
// logits and the 32-bin chunk (8 bins each) for the value mix; partial
// logits are combined with two __shfl_xor ops, softmax is computed
// redundantly (lane-uniform) in all 4 lanes.
// LDS: 2 buffers x 8 g x 256 slots x 16B = 64KB -> 2 blocks/CU x 8 waves
// = 16 waves/CU (50%); grid 512 = exactly 2 blocks/CU.
// Halo rows padded 20->21 float4 (row stride 84 dwords = 20 mod 32) so the
// 4 wave rows land in distinct bank groups; per-g block padded to 256 slots
// so staging index math is shift/mask and DMA dest stays linear.
// OOB: staged addresses CLAMPED (garbage never read); logits of invalid
// neighbors forced to 0 (== reference's zero-padded conv_ref dot) and their
// softmax weights forced to 0 (== zero-padded values).
// ---------------------------------------------------------------------------
#define TH 8
#define TW 16
#define HROW 21        // padded halo row width in float4 (20 real + 1 pad)
#define GSLOT 256      // slots per channel-group (12*21=252 real + 4 pad)
#define NSLOT 2048     // 8 groups * 256 slots per buffer

__global__ __launch_bounds__(512, 4)
void attn_tile_kernel(const float* __restrict__ qm, const float* __restrict__ kr,
                      const float* __restrict__ vv, float* __restrict__ out) {
    __shared__ float4 KS[2][NSLOT];   // 64 KB

    const int t    = threadIdx.x;
    const int wid  = t >> 6;
    const int ln   = t & 63;
    const int part = t & 3;           // channel-quarter owned by this lane
    const int pxi  = t >> 2;          // pixel 0..127 within tile

    const int bi = blockIdx.x >> 7;           // batch
    const int ty = (blockIdx.x >> 3) & 15;    // 16 tile-rows of 8
    const int tx = blockIdx.x & 7;            // 8 tile-cols of 16
    const int h0 = ty * TH, w0 = tx * TW;
    const int r = pxi >> 4, c = pxi & 15;     // r == wid (wave = tile row)
    const int h = h0 + r, w = w0 + c;
    const int gbase = bi * HH * WW;
    const int pix = gbase + h * WW + w;
    const int g0 = part * 2;                  // this lane's float4 groups

    // 25-bit validity mask for this pixel's window
    unsigned vm = 0;
#pragma unroll
    for (int dy = 0; dy < 5; ++dy)
#pragma unroll
        for (int dx = 0; dx < 5; ++dx) {
            const int hh = h + dy - 2, ww = w + dx - 2;
            if ((unsigned)hh < (unsigned)HH && (unsigned)ww < (unsigned)WW)
                vm |= 1u << (dy * 5 + dx);
        }

    auto stage = [&](int p, int buf) {
        const float* src = (p < 4) ? kr : vv;
        const int ld = (p < 4) ? CC : BIN;
        const int ch = (p < 4) ? p * 32 : (p - 4) * 32;
        for (int i = wid; i < NSLOT / 64; i += 8) {
            const int s   = i * 64 + ln;
            const int g   = s >> 8;             // float4 group 0..7
            const int px  = s & 255;            // padded halo slot
            const int py  = px / 21;            // 0..12 (12 = pad row)
            const int pxx = px - py * 21;       // 0..20 (20 = pad col)
            int hh = h0 + py - 2;  hh = hh < 0 ? 0 : (hh > HH - 1 ? HH - 1 : hh);
            int ww = w0 + pxx - 2; ww = ww < 0 ? 0 : (ww > WW - 1 ? WW - 1 : ww);
            const float* gp = src + (size_t)(gbase + hh * WW + ww) * ld + ch + g * 4;
            __builtin_amdgcn_global_load_lds(
                (const __attribute__((address_space(1))) void*)gp,
                (__attribute__((address_space(3))) void*)&KS[buf][i * 64],
                16, 0, 0);
        }
    };

    float lg[25];
#pragma unroll
    for (int i = 0; i < 25; ++i) lg[i] = 0.0f;

    stage(0, 0);
    __syncthreads();

    for (int p = 0; p < 6; ++p) {
        if (p < 5) stage(p + 1, (p + 1) & 1);   // prefetch into other buffer
        const float4* B = KS[p & 1];
        if (p < 4) {
            // ---- logits chunk: 32 channels, this lane's 8 ----
            const float4* qp = (const float4*)(qm + (size_t)pix * CC + p * 32 + part * 8);
            float4 q0 = qp[0], q1 = qp[1];
#pragma unroll
            for (int dy = 0; dy < 5; ++dy)
#pragma unroll
                for (int dx = 0; dx < 5; ++dx) {
                    const int hp = (r + dy) * HROW + (c + dx);
                    float4 k0 = B[g0 * GSLOT + hp];
                    float4 k1 = B[g0 * GSLOT + GSLOT + hp];
                    lg[dy * 5 + dx] += q0.x * k0.x + q0.y * k0.y +
                                       q0.z * k0.z + q0.w * k0.w +
                                       q1.x * k1.x + q1.y * k1.y +
                                       q1.z * k1.z + q1.w * k1.w;
                }
        } else {
            if (p == 4) {
                // combine the 4 channel-quarters' partial logits
#pragma unroll
                for (int kk = 0; kk < 25; ++kk) {
                    float v = lg[kk];
                    v += __shfl_xor(v, 1);
                    v += __shfl_xor(v, 2);
                    lg[kk] = v;
                }
                // mask OOB logits to 0 (exact zero-pad semantics), softmax,
                // then zero the weights of OOB neighbors
#pragma unroll
                for (int kk = 0; kk < 25; ++kk)
                    if (!((vm >> kk) & 1)) lg[kk] = 0.0f;
                float mx = lg[0];
#pragma unroll
                for (int kk = 1; kk < 25; ++kk) mx = fmaxf(mx, lg[kk]);
                float sum = 0.0f;
#pragma unroll
                for (int kk = 0; kk < 25; ++kk) {
                    lg[kk] = __expf(lg[kk] - mx);
                    sum += lg[kk];
                }
                const float inv = 1.0f / sum;
#pragma unroll
                for (int kk = 0; kk < 25; ++kk)
                    lg[kk] = ((vm >> kk) & 1) ? lg[kk] * inv : 0.0f;
            }
            // ---- value-mix chunk: 32 bins, this lane's 8 ----
            float4 a0 = make_float4(0.f, 0.f, 0.f, 0.f);
            float4 a1 = make_float4(0.f, 0.f, 0.f, 0.f);
#pragma unroll
            for (int dy = 0; dy < 5; ++dy)
#pragma unroll
                for (int dx = 0; dx < 5; ++dx) {
                    const float wgt = lg[dy * 5 + dx];
                    const int hp = (r + dy) * HROW + (c + dx);
                    float4 v0 = B[g0 * GSLOT + hp];
                    float4 v1 = B[g0 * GSLOT + GSLOT + hp];
                    a0.x += wgt * v0.x; a0.y += wgt * v0.y;
                    a0.z += wgt * v0.z; a0.w += wgt * v0.w;
                    a1.x += wgt * v1.x; a1.y += wgt * v1.y;
                    a1.z += wgt * v1.z; a1.w += wgt * v1.w;
                }
            float4* op = (float4*)(out + (size_t)pix * BIN + (p - 4) * 32 + part * 8);
            op[0] = a0;
            op[1] = a1;
        }
        __syncthreads();
    }
}

extern "C" void kernel_launch(void* const* d_in, const int* in_sizes, int n_in,
                              void* d_out, int out_size, void* d_ws, size_t ws_size,
                              hipStream_t stream) {
    const float* main_in   = (const float*)d_in[0];
    const float* ref_in    = (const float*)d_in[1];
    const float* ref_value = (const float*)d_in[2];
    const float* W_main    = (const float*)d_in[3];
    const float* W_ref     = (const float*)d_in[4];
    float* out = (float*)d_out;

    float* conv_main = (float*)d_ws;                         // 32 MB
    float* conv_ref  = conv_main + (size_t)NPIX * CC;        // 32 MB

    dim3 gconv(NPIX / 128, 2);   // 1024 blocks = 4/CU
    conv_mfma_kernel<<<gconv, 256, 0, stream>>>(main_in, ref_in, W_main, W_ref,
                                                conv_main, conv_ref);

    // 512 blocks = 2/CU: one 8x16 tile each, 4 threads per pixel
    attn_tile_kernel<<<512, 512, 0, stream>>>(conv_main, conv_ref, ref_value, out);
}

// Round 3
// 174.063 us; speedup vs baseline: 1.1060x; 1.0896x over previous
//
#include <hip/hip_runtime.h>

// Problem dims (fixed by setup_inputs)
#define BATCH 4
#define HH 128
#define WW 128
#define CC 128
#define BIN 64
#define NPIX (BATCH * HH * WW)   // 65536

typedef short bf16x8 __attribute__((ext_vector_type(8)));
typedef float f32x4 __attribute__((ext_vector_type(4)));

// round-to-nearest-even bf16 bits of f
__device__ __forceinline__ unsigned bf_hi(float f) {
    unsigned u = __float_as_uint(f);
    return (u + 0x7fffu + ((u >> 16) & 1u)) >> 16;
}
// A-operand split: per c, k' slots [4c..4c+3] = [xh, xh, xl, xl]
__device__ __forceinline__ uint2 split_aa(float f) {
    unsigned hb = bf_hi(f);
    float lo = f - __uint_as_float(hb << 16);
    unsigned lb = bf_hi(lo);
    return make_uint2(hb | (hb << 16), lb | (lb << 16));
}
// B-operand split: per c, k' slots = [wh, wl, wh, wl] -> same uint twice
__device__ __forceinline__ unsigned split_b(float f) {
    unsigned hb = bf_hi(f);
    float lo = f - __uint_as_float(hb << 16);
    unsigned lb = bf_hi(lo);
    return hb | (lb << 16);
}

// ---------------------------------------------------------------------------
// Kernel 1: 1x1 conv == GEMM via split-bf16 MFMA.
// Y[p][d] = sum_c X[p][c]*W[c][d], fp32 reproduced as (xh+xl)*(wh+wl),
// K'=512 (4 bf16 slots per c). 128px x 128d tile, K' chunked by 64 (16 c).
// Register-prefetch pipeline: global loads for chunk k+1 issued right after
// the stage->MFMA barrier so HBM/L2 latency hides under MFMA + ds_read.
// ---------------------------------------------------------------------------
#define AROW 72   // shorts per LDS row (64 k' + 8 pad)

__global__ __launch_bounds__(256, 4)
void conv_mfma_kernel(const float* __restrict__ Xm, const float* __restrict__ Xr,
                      const float* __restrict__ Wm, const float* __restrict__ Wr,
                      float* __restrict__ Ym, float* __restrict__ Yr) {
    const float* __restrict__ X = blockIdx.y ? Xr : Xm;
    const float* __restrict__ W = blockIdx.y ? Wr : Wm;
    float* __restrict__ Y       = blockIdx.y ? Yr : Ym;

    __shared__ unsigned short AT[128 * AROW];   // [px][k'] 18 KB
    __shared__ unsigned short BT[128 * AROW];   // [d][k']  18 KB

    const int t  = threadIdx.x;
    const int wv = t >> 6;
    const int l  = t & 63;
    const int wm = (wv >> 1) * 64;   // wave's px-quadrant
    const int wn = (wv & 1) * 64;    // wave's d-quadrant
    const int lr = l & 15;
    const int lq = l >> 4;
    const int p_base = blockIdx.x * 128;

    const int px = t >> 1, ahalf = t & 1;   // A staging: 2 thr/px, 8 c each
    const int d  = t & 127, bq = t >> 7;    // B staging: 2 thr/d, 8 c each

    f32x4 acc[4][4] = {};

    const float* xbase = X + (size_t)(p_base + px) * CC + ahalf * 8;

    // ---- prologue: prefetch chunk 0 into registers ----
    float4 xa0 = *(const float4*)(xbase);
    float4 xa1 = *(const float4*)(xbase + 4);
    float wb[8];
#pragma unroll
    for (int j = 0; j < 2; ++j) {
        const int cg = bq * 2 + j;
        const float* wp = W + (size_t)(cg * 4) * CC + d;
        wb[j * 4 + 0] = wp[0];
        wb[j * 4 + 1] = wp[CC];
        wb[j * 4 + 2] = wp[2 * CC];
        wb[j * 4 + 3] = wp[3 * CC];
    }

    for (int kc = 0; kc < CC; kc += 16) {   // 16 c per chunk = 64 k'
        __syncthreads();                    // prev MFMA reads done
        // ---- stage A from regs (fp32 -> [h,h,l,l] bf16) ----
        {
            unsigned short* arow = &AT[px * AROW + ahalf * 32];
            {
                uint2 a0 = split_aa(xa0.x), a1 = split_aa(xa0.y),
                      a2 = split_aa(xa0.z), a3 = split_aa(xa0.w);
                *(uint4*)(arow)     = make_uint4(a0.x, a0.y, a1.x, a1.y);
                *(uint4*)(arow + 8) = make_uint4(a2.x, a2.y, a3.x, a3.y);
            }
            {
                uint2 a0 = split_aa(xa1.x), a1 = split_aa(xa1.y),
                      a2 = split_aa(xa1.z), a3 = split_aa(xa1.w);
                *(uint4*)(arow + 16) = make_uint4(a0.x, a0.y, a1.x, a1.y);
                *(uint4*)(arow + 24) = make_uint4(a2.x, a2.y, a3.x, a3.y);
            }
        }
        // ---- stage B from regs (fp32 -> [h,l,h,l] bf16, [d][k']) ----
        {
#pragma unroll
            for (int j = 0; j < 2; ++j) {
                const int cg = bq * 2 + j;
                unsigned b0 = split_b(wb[j * 4 + 0]);
                unsigned b1 = split_b(wb[j * 4 + 1]);
                unsigned b2 = split_b(wb[j * 4 + 2]);
                unsigned b3 = split_b(wb[j * 4 + 3]);
                unsigned short* brow = &BT[d * AROW + cg * 16];
                *(uint4*)(brow)     = make_uint4(b0, b0, b1, b1);
                *(uint4*)(brow + 8) = make_uint4(b2, b2, b3, b3);
            }
        }
        __syncthreads();
        // ---- prefetch chunk kc+16 (overlaps MFMA below) ----
        if (kc + 16 < CC) {
            const float* xp = xbase + kc + 16;
            xa0 = *(const float4*)(xp);
            xa1 = *(const float4*)(xp + 4);
#pragma unroll
            for (int j = 0; j < 2; ++j) {
                const int cg = bq * 2 + j;
                const float* wp = W + (size_t)(kc + 16 + cg * 4) * CC + d;
                wb[j * 4 + 0] = wp[0];
                wb[j * 4 + 1] = wp[CC];
                wb[j * 4 + 2] = wp[2 * CC];
                wb[j * 4 + 3] = wp[3 * CC];
            }
        }
        // ---- MFMA: 2 k-steps of 32 ----
#pragma unroll
        for (int ks = 0; ks < 2; ++ks) {
            bf16x8 af[4], bfr[4];
#pragma unroll
            for (int mi = 0; mi < 4; ++mi)
                af[mi] = *(const bf16x8*)&AT[(wm + mi * 16 + lr) * AROW + ks * 32 + lq * 8];
#pragma unroll
            for (int ni = 0; ni < 4; ++ni)
                bfr[ni] = *(const bf16x8*)&BT[(wn + ni * 16 + lr) * AROW + ks * 32 + lq * 8];
#pragma unroll
            for (int mi = 0; mi < 4; ++mi)
#pragma unroll
                for (int ni = 0; ni < 4; ++ni)
                    acc[mi][ni] = __builtin_amdgcn_mfma_f32_16x16x32_bf16(
                        af[mi], bfr[ni], acc[mi][ni], 0, 0, 0);
        }
    }

    // epilogue: C/D layout col=lane&15, row=(lane>>4)*4+reg
#pragma unroll
    for (int mi = 0; mi < 4; ++mi)
#pragma unroll
        for (int ni = 0; ni < 4; ++ni)
#pragma unroll
            for (int reg = 0; reg < 4; ++reg) {
                const int row = p_base + wm + mi * 16 + lq * 4 + reg;
                Y[(size_t)row * CC + wn + ni * 16 + lr] = acc[mi][ni][reg];
            }
}

// ---------------------------------------------------------------------------
// Kernel 2: local 5x5 attention, LDS-tiled with async prefetch.
// v3 fixes over v2 (counter-driven):
//  - __launch_bounds__(512,2): v2's (512,4) forced VGPR=64 -> scratch spills
//    (WRITE_SIZE 16.4->34.7MB, FETCH +13MB). Natural usage ~90-110 VGPRs
//    keeps 16 waves/CU (<=128) without spilling.
//  - GSLOT 256->257: v2's group stride 4096B = 0 mod 32 banks made the 4
//    channel-parts of a pixel collide 4-way on every ds_read_b128
//    (SQ_LDS_BANK_CONFLICT 14.75M). 257*16B = 8-bank offset per group ->
//    parts at bank bases {0,8,16,24}, pixels spread by 4 -> worst 2-way.
//    Staging: wave wid DMAs group wid (4 global_load_lds, dest linear).
// Structure: 8x16 tile, 512 thr (4/px), 6 phases (4 K-chunks + 2 V-chunks of
// 32 ch) double-buffered via global_load_lds. LDS 2x2056x16B = 65.8KB ->
// 2 blocks/CU. OOB: staged addrs clamped; logits of invalid neighbors = 0;
// their softmax weights = 0 (exact zero-pad semantics).
// ---------------------------------------------------------------------------
#define TH 8
#define TW 16
#define HROW 21        // padded halo row width in float4 (20 real + 1 pad)
#define GSLOT 257      // slots per channel-group (12*21=252 real + pad), odd*16B bank skew
#define NSLOT (8 * GSLOT)   // 2056 slots per buffer

__global__ __launch_bounds__(512, 2)
void attn_tile_kernel(const float* __restrict__ qm, const float* __restrict__ kr,
                      const float* __restrict__ vv, float* __restrict__ out) {
    __shared__ float4 KS[2][NSLOT];   // 65.8 KB

    const int t    = threadIdx.x;
    const int wid  = t >> 6;
    const int ln   = t & 63;
    const int part = t & 3;           // channel-quarter owned by this lane
    const int pxi  = t >> 2;          // pixel 0..127 within tile

    const int bi = blockIdx.x >> 7;           // batch
    const int ty = (blockIdx.x >> 3) & 15;    // 16 tile-rows of 8
    const int tx = blockIdx.x & 7;            // 8 tile-cols of 16
    const int h0 = ty * TH, w0 = tx * TW;
    const int r = pxi >> 4, c = pxi & 15;
    const int h = h0 + r, w = w0 + c;
    const int gbase = bi * HH * WW;
    const int pix = gbase + h * WW + w;
    const int g0 = part * 2;                  // this lane's float4 groups

    // 25-bit validity mask for this pixel's window
    unsigned vm = 0;
#pragma unroll
    for (int dy = 0; dy < 5; ++dy)
#pragma unroll
        for (int dx = 0; dx < 5; ++dx) {
            const int hh = h + dy - 2, ww = w + dx - 2;
            if ((unsigned)hh < (unsigned)HH && (unsigned)ww < (unsigned)WW)
                vm |= 1u << (dy * 5 + dx);
        }

    // wave wid stages channel-group wid: 4 DMA chunks of 64 slots cover the
    // 252 real halo slots (+4 clamped pads). DMA dest = uniform base + ln*16.
    auto stage = [&](int p, int buf) {
        const float* src = (p < 4) ? kr : vv;
        const int ld = (p < 4) ? CC : BIN;
        const int ch = ((p < 4) ? p * 32 : (p - 4) * 32) + wid * 4;
#pragma unroll
        for (int i = 0; i < 4; ++i) {
            const int px  = i * 64 + ln;        // halo slot 0..255
            const int py  = px / 21;            // 0..12 (12 = pad row)
            const int pxx = px - py * 21;       // 0..20 (20 = pad col)
            int hh = h0 + py - 2;  hh = hh < 0 ? 0 : (hh > HH - 1 ? HH - 1 : hh);
            int ww = w0 + pxx - 2; ww = ww < 0 ? 0 : (ww > WW - 1 ? WW - 1 : ww);
            const float* gp = src + (size_t)(gbase + hh * WW + ww) * ld + ch;
            __builtin_amdgcn_global_load_lds(
                (const __attribute__((address_space(1))) void*)gp,
                (__attribute__((address_space(3))) void*)&KS[buf][wid * GSLOT + i * 64],
                16, 0, 0);
        }
    };

    float lg[25];
#pragma unroll
    for (int i = 0; i < 25; ++i) lg[i] = 0.0f;

    stage(0, 0);
    __syncthreads();

    for (int p = 0; p < 6; ++p) {
        if (p < 5) stage(p + 1, (p + 1) & 1);   // prefetch into other buffer
        const float4* B = KS[p & 1];
        if (p < 4) {
            // ---- logits chunk: 32 channels, this lane's 8 ----
            const float4* qp = (const float4*)(qm + (size_t)pix * CC + p * 32 + part * 8);
            float4 q0 = qp[0], q1 = qp[1];
#pragma unroll
            for (int dy = 0; dy < 5; ++dy)
#pragma unroll
                for (int dx = 0; dx < 5; ++dx) {
                    const int hp = (r + dy) * HROW + (c + dx);
                    float4 k0 = B[g0 * GSLOT + hp];
                    float4 k1 = B[g0 * GSLOT + GSLOT + hp];
                    lg[dy * 5 + dx] += q0.x * k0.x + q0.y * k0.y +
                                       q0.z * k0.z + q0.w * k0.w +
                                       q1.x * k1.x + q1.y * k1.y +
                                       q1.z * k1.z + q1.w * k1.w;
                }
        } else {
            if (p == 4) {
                // combine the 4 channel-quarters' partial logits
#pragma unroll
                for (int kk = 0; kk < 25; ++kk) {
                    float v = lg[kk];
                    v += __shfl_xor(v, 1);
                    v += __shfl_xor(v, 2);
                    lg[kk] = v;
                }
                // mask OOB logits to 0 (exact zero-pad semantics), softmax,
                // then zero the weights of OOB neighbors
#pragma unroll
                for (int kk = 0; kk < 25; ++kk)
                    if (!((vm >> kk) & 1)) lg[kk] = 0.0f;
                float mx = lg[0];
#pragma unroll
                for (int kk = 1; kk < 25; ++kk) mx = fmaxf(mx, lg[kk]);
                float sum = 0.0f;
#pragma unroll
                for (int kk = 0; kk < 25; ++kk) {
                    lg[kk] = __expf(lg[kk] - mx);
                    sum += lg[kk];
                }
                const float inv = 1.0f / sum;
#pragma unroll
                for (int kk = 0; kk < 25; ++kk)
                    lg[kk] = ((vm >> kk) & 1) ? lg[kk] * inv : 0.0f;
            }
            // ---- value-mix chunk: 32 bins, this lane's 8 ----
            float4 a0 = make_float4(0.f, 0.f, 0.f, 0.f);
            float4 a1 = make_float4(0.f, 0.f, 0.f, 0.f);
#pragma unroll
            for (int dy = 0; dy < 5; ++dy)
#pragma unroll
                for (int dx = 0; dx < 5; ++dx) {
                    const float wgt = lg[dy * 5 + dx];
                    const int hp = (r + dy) * HROW + (c + dx);
                    float4 v0 = B[g0 * GSLOT + hp];
                    float4 v1 = B[g0 * GSLOT + GSLOT + hp];
                    a0.x += wgt * v0.x; a0.y += wgt * v0.y;
                    a0.z += wgt * v0.z; a0.w += wgt * v0.w;
                    a1.x += wgt * v1.x; a1.y += wgt * v1.y;
                    a1.z += wgt * v1.z; a1.w += wgt * v1.w;
                }
            float4* op = (float4*)(out + (size_t)pix * BIN + (p - 4) * 32 + part * 8);
            op[0] = a0;
            op[1] = a1;
        }
        __syncthreads();
    }
}

extern "C" void kernel_launch(void* const* d_in, const int* in_sizes, int n_in,
                              void* d_out, int out_size, void* d_ws, size_t ws_size,
                              hipStream_t stream) {
    const float* main_in   = (const float*)d_in[0];
    const float* ref_in    = (const float*)d_in[1];
    const float* ref_value = (const float*)d_in[2];
    const float* W_main    = (const float*)d_in[3];
    const float* W_ref     = (const float*)d_in[4];
    float* out = (float*)d_out;

    float* conv_main = (float*)d_ws;                         // 32 MB
    float* conv_ref  = conv_main + (size_t)NPIX * CC;        // 32 MB

    dim3 gconv(NPIX / 128, 2);   // 1024 blocks = 4/CU
    conv_mfma_kernel<<<gconv, 256, 0, stream>>>(main_in, ref_in, W_main, W_ref,
                                                conv_main, conv_ref);

    // 512 blocks = 2/CU: one 8x16 tile each, 4 threads per pixel
    attn_tile_kernel<<<512, 512, 0, stream>>>(conv_main, conv_ref, ref_value, out);
}